// Round 5
// baseline (290.149 us; speedup 1.0000x reference)
//
#include <hip/hip_runtime.h>
#include <hip/hip_cooperative_groups.h>

namespace cg = cooperative_groups;

// BATCH=65536, DIM=512, NUM_CLASSES=1000, NUM_OLD=500
constexpr int kDim = 512;
constexpr int kF4PerRow = kDim / 4;  // 128 float4/row
constexpr int kBlocks = 512;         // 2 blocks/CU, 8 waves/CU — co-resident for grid.sync

// Native clang vector type — required by __builtin_nontemporal_load
typedef float f32x4 __attribute__((ext_vector_type(4)));

__device__ __forceinline__ float sqdiff4(f32x4 e, f32x4 c) {
    f32x4 d = e - c;
    d = d * d;
    return d.x + d.y + d.z + d.w;
}

// Wave-pair scheme: each 64-sample chunk is serviced by a pair of waves, each
// covering 64 of the 128 float4 columns. Embedding reads are nontemporal
// (streamed once); centroid reads use the normal cached path (2 MB, hot in L2).
__global__ __launch_bounds__(256) void mse_fused_kernel(
    const float* __restrict__ emb,
    const float* __restrict__ cen,
    const int* __restrict__ labels,
    const int* __restrict__ num_old_p,
    int batch,
    float* __restrict__ ws_sum,
    unsigned int* __restrict__ ws_cnt,
    float* __restrict__ out)
{
    const int num_old = *num_old_p;
    const int lane = threadIdx.x & 63;
    const int wid  = threadIdx.x >> 6;
    const int wpb  = blockDim.x >> 6;
    const int gwave = blockIdx.x * wpb + wid;
    const int nwave = gridDim.x * wpb;

    const int half = gwave & 1;            // which 64-float4 half of each row
    const int col  = half * 64 + lane;     // this wave's float4 column

    const f32x4* __restrict__ emb4 = (const f32x4*)emb;
    const f32x4* __restrict__ cen4 = (const f32x4*)cen;

    float acc = 0.0f;
    unsigned int cnt = 0;

    const int nchunks = (batch + 63) >> 6;
    for (int ch = (gwave >> 1); ch < nchunks; ch += (nwave >> 1)) {
        const int chunk = ch * 64;
        const int idx = chunk + lane;
        const int mylab = (idx < batch) ? labels[idx] : 0x7fffffff;
        unsigned long long m = __ballot(mylab < num_old);
        if (half == 0) cnt += (unsigned int)__popcll(m);   // count once per pair

        // 8 masked rows in flight: 16 independent 16B loads per burst.
        while (__popcll(m) >= 8) {
            int b[8], l[8];
            #pragma unroll
            for (int i = 0; i < 8; ++i) { b[i] = __builtin_ctzll(m); m &= m - 1; }
            #pragma unroll
            for (int i = 0; i < 8; ++i) l[i] = __shfl(mylab, b[i], 64);

            f32x4 e[8], c[8];
            #pragma unroll
            for (int i = 0; i < 8; ++i)
                e[i] = __builtin_nontemporal_load(&emb4[(size_t)(chunk + b[i]) * kF4PerRow + col]);
            #pragma unroll
            for (int i = 0; i < 8; ++i)
                c[i] = cen4[(size_t)l[i] * kF4PerRow + col];

            #pragma unroll
            for (int i = 0; i < 8; ++i)
                acc += sqdiff4(e[i], c[i]);
        }
        // Remainder rows.
        while (m) {
            const int b = __builtin_ctzll(m); m &= m - 1;
            const int l = __shfl(mylab, b, 64);
            f32x4 e = __builtin_nontemporal_load(&emb4[(size_t)(chunk + b) * kF4PerRow + col]);
            f32x4 c = cen4[(size_t)l * kF4PerRow + col];
            acc += sqdiff4(e, c);
        }
    }

    // Wave butterfly reduce
    #pragma unroll
    for (int off = 32; off > 0; off >>= 1)
        acc += __shfl_xor(acc, off, 64);

    __shared__ float        s_sum[4];
    __shared__ unsigned int s_cnt[4];
    if (lane == 0) { s_sum[wid] = acc; s_cnt[wid] = cnt; }
    __syncthreads();

    if (threadIdx.x == 0) {
        float        bs = 0.0f;
        unsigned int bc = 0u;
        for (int i = 0; i < wpb; ++i) { bs += s_sum[i]; bc += s_cnt[i]; }
        ws_sum[blockIdx.x] = bs;
        ws_cnt[blockIdx.x] = bc;
    }
    __threadfence();            // make partials device-visible before grid sync

    cg::this_grid().sync();

    // Block 0 reduces the per-block partials and writes the scalar output.
    if (blockIdx.x == 0) {
        const int t = threadIdx.x;
        float        s = 0.0f;
        unsigned int c = 0u;
        for (int i = t; i < kBlocks; i += blockDim.x) { s += ws_sum[i]; c += ws_cnt[i]; }

        #pragma unroll
        for (int off = 32; off > 0; off >>= 1) {
            s += __shfl_xor(s, off, 64);
            c += __shfl_xor(c, off, 64);
        }
        __shared__ float        ls[4];
        __shared__ unsigned int lc[4];
        if (lane == 0) { ls[wid] = s; lc[wid] = c; }
        __syncthreads();
        if (t == 0) {
            float        ts = ls[0] + ls[1] + ls[2] + ls[3];
            unsigned int tc = lc[0] + lc[1] + lc[2] + lc[3];
            const float total = ts * (1.0f / (float)kDim);
            out[0] = (tc == 0u) ? total : total / (float)tc;
        }
    }
}

extern "C" void kernel_launch(void* const* d_in, const int* in_sizes, int n_in,
                              void* d_out, int out_size, void* d_ws, size_t ws_size,
                              hipStream_t stream) {
    const float* emb       = (const float*)d_in[0];  // [65536, 512] f32
    const float* cen       = (const float*)d_in[1];  // [1000, 512]  f32
    const int*   labels    = (const int*)d_in[2];    // [65536] i32
    const int*   num_old_p = (const int*)d_in[3];    // scalar i32
    int batch = in_sizes[2];

    float*        ws_sum = (float*)d_ws;
    unsigned int* ws_cnt = (unsigned int*)((char*)d_ws + kBlocks * sizeof(float));
    float*        out    = (float*)d_out;

    void* args[] = { (void*)&emb, (void*)&cen, (void*)&labels, (void*)&num_old_p,
                     (void*)&batch, (void*)&ws_sum, (void*)&ws_cnt, (void*)&out };
    (void)hipLaunchCooperativeKernel((const void*)mse_fused_kernel,
                                     dim3(kBlocks), dim3(256), args, 0, stream);
}

// Round 6
// 186.016 us; speedup vs baseline: 1.5598x; 1.5598x over previous
//
#include <hip/hip_runtime.h>

// BATCH=65536, DIM=512, NUM_CLASSES=1000, NUM_OLD=500
constexpr int kDim = 512;
constexpr int kF4PerRow = kDim / 4;  // 128 float4/row; wave64 -> 2 float4/lane

__device__ __forceinline__ float sqdiff8(float4 e0, float4 e1, float4 c0, float4 c1) {
    float d, t;
    d = e0.x - c0.x; t  = d * d;
    d = e0.y - c0.y; t += d * d;
    d = e0.z - c0.z; t += d * d;
    d = e0.w - c0.w; t += d * d;
    d = e1.x - c1.x; t += d * d;
    d = e1.y - c1.y; t += d * d;
    d = e1.z - c1.z; t += d * d;
    d = e1.w - c1.w; t += d * d;
    return t;
}

__global__ __launch_bounds__(256) void mse_masked_kernel(
    const float* __restrict__ emb,
    const float* __restrict__ cen,
    const int* __restrict__ labels,
    const int* __restrict__ num_old_p,
    int batch,
    float* __restrict__ ws_sum,
    unsigned int* __restrict__ ws_cnt)
{
    const int num_old = *num_old_p;
    const int lane = threadIdx.x & 63;
    const int wid  = threadIdx.x >> 6;
    const int wpb  = blockDim.x >> 6;
    const int gwave = blockIdx.x * wpb + wid;
    const int nwave = gridDim.x * wpb;

    const float4* __restrict__ emb4 = (const float4*)emb;
    const float4* __restrict__ cen4 = (const float4*)cen;

    float acc = 0.0f;
    unsigned int cnt = 0;

    // Each wave owns 64-sample chunks, grid-strided.
    for (int chunk = gwave * 64; chunk < batch; chunk += nwave * 64) {
        const int idx = chunk + lane;
        // One coalesced 64-label load per chunk (no per-sample dependent load).
        const int mylab = (idx < batch) ? labels[idx] : 0x7fffffff;
        unsigned long long m = __ballot(mylab < num_old);
        cnt += (unsigned int)__popcll(m);

        // 4 rows in flight: 16 independent 16B loads issued before any use.
        while (__popcll(m) >= 4) {
            const int b0 = __builtin_ctzll(m); m &= m - 1;
            const int b1 = __builtin_ctzll(m); m &= m - 1;
            const int b2 = __builtin_ctzll(m); m &= m - 1;
            const int b3 = __builtin_ctzll(m); m &= m - 1;
            const int l0 = __shfl(mylab, b0, 64);
            const int l1 = __shfl(mylab, b1, 64);
            const int l2 = __shfl(mylab, b2, 64);
            const int l3 = __shfl(mylab, b3, 64);

            const float4* e0p = emb4 + (size_t)(chunk + b0) * kF4PerRow;
            const float4* e1p = emb4 + (size_t)(chunk + b1) * kF4PerRow;
            const float4* e2p = emb4 + (size_t)(chunk + b2) * kF4PerRow;
            const float4* e3p = emb4 + (size_t)(chunk + b3) * kF4PerRow;
            const float4* c0p = cen4 + (size_t)l0 * kF4PerRow;
            const float4* c1p = cen4 + (size_t)l1 * kF4PerRow;
            const float4* c2p = cen4 + (size_t)l2 * kF4PerRow;
            const float4* c3p = cen4 + (size_t)l3 * kF4PerRow;

            float4 ea0 = e0p[lane], eb0 = e0p[lane + 64];
            float4 ea1 = e1p[lane], eb1 = e1p[lane + 64];
            float4 ea2 = e2p[lane], eb2 = e2p[lane + 64];
            float4 ea3 = e3p[lane], eb3 = e3p[lane + 64];
            float4 ca0 = c0p[lane], cb0 = c0p[lane + 64];
            float4 ca1 = c1p[lane], cb1 = c1p[lane + 64];
            float4 ca2 = c2p[lane], cb2 = c2p[lane + 64];
            float4 ca3 = c3p[lane], cb3 = c3p[lane + 64];

            acc += sqdiff8(ea0, eb0, ca0, cb0);
            acc += sqdiff8(ea1, eb1, ca1, cb1);
            acc += sqdiff8(ea2, eb2, ca2, cb2);
            acc += sqdiff8(ea3, eb3, ca3, cb3);
        }
        // Remainder rows one at a time.
        while (m) {
            const int b = __builtin_ctzll(m); m &= m - 1;
            const int l = __shfl(mylab, b, 64);
            const float4* ep = emb4 + (size_t)(chunk + b) * kF4PerRow;
            const float4* cp = cen4 + (size_t)l * kF4PerRow;
            float4 e0 = ep[lane], e1 = ep[lane + 64];
            float4 c0 = cp[lane], c1 = cp[lane + 64];
            acc += sqdiff8(e0, e1, c0, c1);
        }
    }

    // Wave butterfly reduce
    #pragma unroll
    for (int off = 32; off > 0; off >>= 1)
        acc += __shfl_xor(acc, off, 64);

    __shared__ float        s_sum[4];
    __shared__ unsigned int s_cnt[4];
    if (lane == 0) { s_sum[wid] = acc; s_cnt[wid] = cnt; }
    __syncthreads();

    if (threadIdx.x == 0) {
        float        bs = 0.0f;
        unsigned int bc = 0u;
        for (int i = 0; i < wpb; ++i) { bs += s_sum[i]; bc += s_cnt[i]; }
        // Plain per-block stores into distinct slots -> no zero-init kernel needed.
        ws_sum[blockIdx.x] = bs;
        ws_cnt[blockIdx.x] = bc;
    }
}

__global__ __launch_bounds__(256) void finalize_kernel(
    const float* __restrict__ ws_sum,
    const unsigned int* __restrict__ ws_cnt,
    int nparts,
    float* __restrict__ out)
{
    const int t = threadIdx.x;
    float        s = (t < nparts) ? ws_sum[t] : 0.0f;
    unsigned int c = (t < nparts) ? ws_cnt[t] : 0u;

    #pragma unroll
    for (int off = 32; off > 0; off >>= 1) {
        s += __shfl_xor(s, off, 64);
        c += __shfl_xor(c, off, 64);
    }
    __shared__ float        ls[4];
    __shared__ unsigned int lc[4];
    const int lane = t & 63, wid = t >> 6;
    if (lane == 0) { ls[wid] = s; lc[wid] = c; }
    __syncthreads();
    if (t == 0) {
        float        ts = ls[0] + ls[1] + ls[2] + ls[3];
        unsigned int tc = lc[0] + lc[1] + lc[2] + lc[3];
        const float total = ts * (1.0f / (float)kDim);
        out[0] = (tc == 0u) ? total : total / (float)tc;
    }
}

extern "C" void kernel_launch(void* const* d_in, const int* in_sizes, int n_in,
                              void* d_out, int out_size, void* d_ws, size_t ws_size,
                              hipStream_t stream) {
    const float* emb       = (const float*)d_in[0];  // [65536, 512] f32
    const float* cen       = (const float*)d_in[1];  // [1000, 512]  f32
    const int*   labels    = (const int*)d_in[2];    // [65536] i32
    const int*   num_old_p = (const int*)d_in[3];    // scalar i32

    const int batch = in_sizes[2];

    const int blocks = 256;  // 256 blocks x 4 waves = 1024 waves = one 64-chunk each at B=65536
    float*        ws_sum = (float*)d_ws;
    unsigned int* ws_cnt = (unsigned int*)((char*)d_ws + blocks * sizeof(float));

    mse_masked_kernel<<<blocks, 256, 0, stream>>>(emb, cen, labels, num_old_p,
                                                  batch, ws_sum, ws_cnt);
    finalize_kernel<<<1, 256, 0, stream>>>(ws_sum, ws_cnt, blocks, (float*)d_out);
}